// Round 13
// baseline (25490.947 us; speedup 1.0000x reference)
//
#include <hip/hip_runtime.h>
#include <cstddef>

#define DEV __device__ __forceinline__

// ---- dims: B=16 S=256 IN_DIM=264 H=512 4H=2048 XI=471 N=256 M=64 R=4 OUT=256
constexpr int S_ = 256;
constexpr int NB = 256;
constexpr int NT = 256;

// R12 post-mortem: FETCH collapsed 27x, time unchanged -> bytes not the wall;
// serial sync hops are (~3.7us per sys hop measured R10->R12). R13: fuse LSTM
// into gates blocks (col remap: block owns all 4 quadrant cols of 32
// h-indices, (col>>3)&7==x keeps the 1.06MB/XCD slice L2-resident), deleting
// the gates sys round-trip, the gct hop, phase A2 and its cbar. y(t-1) moves
// to B's head (overlaps h-wait). Chain: stf -> G+LSTM -> hcnt -> B -> cbar ->
// C -> cbar -> D -> cbar -> E -> cbar (~6 hops, was 8).

// per-batch region offsets (floats), stride PB, base ws + b*PB
constexpr size_t bH    = 0;       // 2x512 h ping-pong [sys; written by gates blocks]
constexpr size_t bC    = 1024;    // 512 LSTM c [private: gates block (x,s)]
constexpr size_t bXI   = 1536;    // 512 (471 used) [agent]
constexpr size_t bKNR  = 2048;    // 256 [agent]
constexpr size_t bALC  = 2304;    // 256 [agent]
constexpr size_t bCW   = 2560;    // 256 [agent]
constexpr size_t bWW   = 2816;    // 256 [agent]
constexpr size_t bNRM  = 3072;    // 256 [agent]
constexpr size_t bUSG  = 3328;    // 256 [private: ctrl block]
constexpr size_t bRV   = 3584;    // 256 [sys]
constexpr size_t bYH   = 3840;    // 256 [agent]
constexpr size_t bSCL  = 4096;    // 32  [agent]
constexpr size_t bPI   = 4128;    // 32  [agent]
constexpr size_t bERS  = 4160;    // 64  [agent]
constexpr size_t bWVC  = 4224;    // 64  [agent]
constexpr size_t bPRC  = 4288;    // 2x256 [agent]
constexpr size_t bWR   = 4800;    // 4x256 [agent]
constexpr size_t bFWD  = 5824;    // 4x256 [agent]
constexpr size_t bBWDP = 6848;    // 4 slots x 4 heads x 256 [agent zero + dev atomicAdd + agent read]
constexpr size_t bFLG  = 10944;   // 16 crew flags x 32 (1/128B line)
constexpr size_t bMEM  = 11456;   // 256x64 [agent]
constexpr size_t bLNK  = 27840;   // 256x256 [private: crew block ci owns rows 16ci..]
constexpr size_t bHCT  = 93376;   // h arrival counter [dev atomicAdd + sys poll]
constexpr size_t bSTF  = 93408;   // state flag (rv of step t done) [sys]
constexpr size_t PB    = 93440;
constexpr size_t WS_TOTAL = PB*16;   // ~5.98 MB

typedef unsigned long long u64_;
union F2U { u64_ u; float2 f; };
DEV float2 ld2_agt(const float* p){ F2U c; c.u=__hip_atomic_load((const u64_*)p,__ATOMIC_RELAXED,__HIP_MEMORY_SCOPE_AGENT); return c.f; }
DEV void   st2_agt(float* p, float2 v){ F2U c; c.f=v; __hip_atomic_store((u64_*)p,c.u,__ATOMIC_RELAXED,__HIP_MEMORY_SCOPE_AGENT); }
DEV float  ld_agt(const float* p){ return __hip_atomic_load((float*)p,__ATOMIC_RELAXED,__HIP_MEMORY_SCOPE_AGENT); }
DEV void   st_agt(float* p,float v){ __hip_atomic_store(p,v,__ATOMIC_RELAXED,__HIP_MEMORY_SCOPE_AGENT); }
DEV float  ld_sys(const float* p){ return __hip_atomic_load((float*)p,__ATOMIC_RELAXED,__HIP_MEMORY_SCOPE_SYSTEM); }
DEV void   st_sys(float* p,float v){ __hip_atomic_store(p,v,__ATOMIC_RELAXED,__HIP_MEMORY_SCOPE_SYSTEM); }

DEV float sigm(float x){ return 1.0f/(1.0f+expf(-x)); }
DEV float oneplus_(float x){ float sp = (x>20.0f)? x : log1pf(expf(x)); return 1.0f+sp; }

DEV float wredsum(float v){
  #pragma unroll
  for (int o=32;o>0;o>>=1) v += __shfl_xor(v,o);
  return v;
}
DEV float hredsum32(float v){
  #pragma unroll
  for (int o=16;o>0;o>>=1) v += __shfl_xor(v,o);
  return v;
}
DEV float wredmax(float v){
  #pragma unroll
  for (int o=32;o>0;o>>=1) v = fmaxf(v,__shfl_xor(v,o));
  return v;
}
DEV float bredsum(float v, float* red){
  v = wredsum(v);
  if ((threadIdx.x&63)==0) red[threadIdx.x>>6]=v;
  __syncthreads();
  float r = red[0]+red[1]+red[2]+red[3];
  __syncthreads();
  return r;
}
DEV float bredmax(float v, float* red){
  v = wredmax(v);
  if ((threadIdx.x&63)==0) red[threadIdx.x>>6]=v;
  __syncthreads();
  float r = fmaxf(fmaxf(red[0],red[1]),fmaxf(red[2],red[3]));
  __syncthreads();
  return r;
}

// crew barrier, single-round (R10-proven): post own flag, all poll all 16.
DEV void cbar(float* wsb, unsigned ep, int ci){
  unsigned* flg = (unsigned*)(wsb + bFLG);
  __syncthreads();
  if (threadIdx.x < 64){
    if (threadIdx.x == 0)
      __hip_atomic_store(flg + (size_t)ci*32, ep, __ATOMIC_RELAXED, __HIP_MEMORY_SCOPE_AGENT);
    const int l = threadIdx.x;
    bool ok;
    do {
      unsigned v = (l<16) ? __hip_atomic_load(flg + (size_t)l*32,
                      __ATOMIC_RELAXED, __HIP_MEMORY_SCOPE_AGENT) : ep;
      ok = __all(v >= ep);
      if (!ok) __builtin_amdgcn_s_sleep(1);
    } while (!ok);
  }
  __syncthreads();
}

__global__ void k_zero(float* __restrict__ ws){
  size_t i = (size_t)blockIdx.x*blockDim.x + threadIdx.x;
  size_t st = (size_t)gridDim.x*blockDim.x;
  for (; i<WS_TOTAL; i+=st) ws[i]=0.0f;
}

__global__ __launch_bounds__(NT, 2) void k_dnc(
    const float* __restrict__ xin, const float* __restrict__ Wx,
    const float* __restrict__ Wh,  const float* __restrict__ bl,
    const float* __restrict__ Wxi, const float* __restrict__ bxi,
    const float* __restrict__ Wy,  const float* __restrict__ Wr,
    const float* __restrict__ by,  float* __restrict__ out,
    float* __restrict__ ws)
{
  __shared__ float smem[14336];   // 57 KB
  const int tid  = threadIdx.x;
  const int bid  = blockIdx.x;
  const int lane = tid & 63, wv = tid >> 6;
  // crew mapping (R9..R12-proven): XCD x = bid%8; q=bid/8; s=q&1; ci=q>>1; b=x+8s
  const int x  = bid & 7;
  const int q  = bid >> 3;
  const int s  = q & 1;
  const int ci = q >> 1;
  const int b  = x + (s<<3);
  float* wsb = ws + (size_t)b*PB;
  // gates role: this block computes, for batch gb=ci, the 32 h-indices
  // J = { (x<<3) + (((s<<2)+m)<<6) + r : m in [0,4), r in [0,8) } and their
  // 4 quadrant gate cols, then the LSTM for J. All cols satisfy
  // (col>>3)&7 == x -> XCD x's weight slice = 1.06MB, L2-resident.
  const int gb = ci;
  float* wsg = ws + (size_t)gb*PB;
  unsigned ep = 0;

  for (int t=0; t<S_; ++t){
    // ================= G: distributed gates GEMM + fused LSTM =================
    {
      unsigned* stf = (unsigned*)(wsg + bSTF);
      if (tid==0){
        while (__hip_atomic_load(stf, __ATOMIC_RELAXED, __HIP_MEMORY_SCOPE_SYSTEM) < (unsigned)t)
          __builtin_amdgcn_s_sleep(1);
      }
      __syncthreads();
      float* sact = smem;          // 1032 (pad 1040)
      float* sred = smem + 1040;   // 256
      float* g4   = smem + 1296;   // 128
      const float* hrd = wsg + bH + (size_t)(t&1)*512;
      for (int e=tid; e<1032; e+=NT){
        float v;
        if (e < 264)      v = xin[((size_t)(gb*256+t))*264 + e];
        else if (e < 520) v = ld_sys(wsg + bRV + (e-264));
        else              v = ld_sys(hrd + (e-520));
        sact[e] = v;
      }
      __syncthreads();
      // 2-way ksplit x 128 cols, unroll-16 prefetch (L2-resident slice)
      {
        const int ks2 = tid>>7, cc = tid&127;
        const int Q = cc>>5, mm = (cc>>3)&3, r = cc&7;
        const int col = (Q<<9) + (x<<3) + (((s<<2)+mm)<<6) + r;
        const float* W; const float* xp; int kn;
        if (ks2==0){ W = Wx + col; xp = sact;       kn = 520; }
        else       { W = Wh + col; xp = sact + 520; kn = 512; }
        float acc = 0.f;
        float buf[16];
        const int nch = (kn+15)>>4;
        #pragma unroll
        for (int i=0;i<16;++i){
          int kk = (i<kn)? i : kn-1;
          buf[i] = W[(size_t)kk*2048];
        }
        for (int c2=0; c2<nch; ++c2){
          float nb[16];
          int nb0 = (c2+1)<<4;
          #pragma unroll
          for (int i=0;i<16;++i){
            int kk = nb0+i; kk = (kk<kn)? kk : kn-1;
            nb[i] = W[(size_t)kk*2048];
          }
          int kb = c2<<4;
          #pragma unroll
          for (int i=0;i<16;++i){
            float xv = (kb+i<kn)? xp[kb+i] : 0.f;
            acc = fmaf(buf[i], xv, acc);
          }
          #pragma unroll
          for (int i=0;i<16;++i) buf[i]=nb[i];
        }
        sred[tid] = acc;
      }
      __syncthreads();
      if (tid < 128){
        const int Q = tid>>5, mm = (tid>>3)&3, r = tid&7;
        const int col = (Q<<9) + (x<<3) + (((s<<2)+mm)<<6) + r;
        g4[tid] = sred[tid] + sred[128+tid] + bl[col];
      }
      __syncthreads();
      if (tid < 32){
        int j = (x<<3) + (((s<<2)+(tid>>3))<<6) + (tid&7);
        float gi=g4[tid], gf=g4[32+tid], gg2=g4[64+tid], go=g4[96+tid];
        float co = wsg[bC + j];          // private to this gates block
        float cn = sigm(gf)*co + sigm(gi)*tanhf(gg2);
        float hn = sigm(go)*tanhf(cn);
        wsg[bC + j] = cn;
        st_sys(wsg + bH + (size_t)((t+1)&1)*512 + j, hn);
      }
      __syncthreads();   // drain h stores (vmcnt 0) before arrival
      if (tid==0) atomicAdd((unsigned*)(wsg + bHCT), 1u);
    }

    // ================= B: y(t-1) (no wait) ; then xi/YH after h arrives =================
    {
      float* srv  = smem;        // 256
      float* ysum = smem + 256;  // 256
      if (t > 0){
        for (int e=tid;e<256;e+=NT) srv[e]=ld_sys(wsb+bRV+e);
        __syncthreads();
        int ks2 = tid>>4, cc = tid&15;
        int yc = (ci<<4) + cc;
        float a = 0.f;
        const float* wp = Wr + (size_t)(ks2*16)*256 + yc;
        const float* rp = srv + ks2*16;
        #pragma unroll
        for (int k=0;k<16;++k) a = fmaf(rp[k], wp[(size_t)k*256], a);
        ysum[ks2*16 + cc] = a;
        __syncthreads();
        if (tid < 16){
          float sm = 0.f;
          #pragma unroll
          for (int p=0;p<16;++p) sm += ysum[p*16 + tid];
          int yc2 = (ci<<4) + tid;
          out[((size_t)(b*256 + (t-1)))*256 + yc2] = ld_agt(wsb+bYH+yc2) + sm;
        }
        __syncthreads();
      }
      unsigned* hct = (unsigned*)(wsb + bHCT);
      if (tid==0){
        while (__hip_atomic_load(hct, __ATOMIC_RELAXED, __HIP_MEMORY_SCOPE_SYSTEM) < 16u*(unsigned)(t+1))
          __builtin_amdgcn_s_sleep(1);
      }
      __syncthreads();
      float* shh = smem;         // 512
      float* sp  = smem + 512;   // 8x30
      float* syh = smem + 768;   // 16x16
      const float* hcur = wsb + bH + (size_t)((t+1)&1)*512;
      for (int e=tid; e<512; e+=NT) shh[e] = ld_sys(hcur + e);
      __syncthreads();
      const int nc = (ci<15) ? 30 : 21;
      if (tid < 240){
        int ks = tid/30, cc = tid%30;
        if (cc < nc){
          int col = ci*30 + cc;
          float a = 0.f;
          const float* wp = Wxi + (size_t)(ks*64)*471 + col;
          const float* hp = shh + ks*64;
          #pragma unroll 8
          for (int k=0;k<64;++k) a = fmaf(hp[k], wp[(size_t)k*471], a);
          sp[ks*30 + cc] = a;
        }
      }
      {
        int ks = tid>>4, cc = tid&15;
        int col = (ci<<4) + cc;
        float a = 0.f;
        const float* wp = Wy + (size_t)(ks*32)*256 + col;
        const float* hp = shh + ks*32;
        #pragma unroll 8
        for (int k=0;k<32;++k) a = fmaf(hp[k], wp[(size_t)k*256], a);
        syh[ks*16 + cc] = a;
      }
      __syncthreads();
      if (tid < nc){
        float sm = bxi[ci*30 + tid];
        #pragma unroll
        for (int p=0;p<8;++p) sm += sp[p*30 + tid];
        st_agt(wsb + bXI + ci*30 + tid, sm);
      }
      if (tid < 16){
        float sm = by[(ci<<4) + tid];
        #pragma unroll
        for (int p=0;p<16;++p) sm += syh[p*16 + tid];
        st_agt(wsb + bYH + (ci<<4) + tid, sm);
      }
    }
    ep++; cbar(wsb, ep, ci);

    // ================= C: ctrl(ci0) | content(ci1) | zero BWDP(ci2) =================
    if (ci == 0){
      float* xv = smem; float* uu = smem+512; float* sa = smem+768;
      float* sb = smem+1024; float* red = smem+1280;
      if (tid < 240){
        float2 v = ld2_agt(wsb + bXI + (tid<<1));
        xv[tid<<1]=v.x; xv[(tid<<1)+1]=v.y;
      }
      __syncthreads();
      int n = tid;
      float f0=sigm(xv[453]), f1=sigm(xv[454]), f2v=sigm(xv[455]), f3=sigm(xv[456]);
      const float* wrb = wsb + bWR;
      float psi=(1.f-f0*ld_agt(wrb+n))*(1.f-f1*ld_agt(wrb+256+n))
               *(1.f-f2v*ld_agt(wrb+512+n))*(1.f-f3*ld_agt(wrb+768+n));
      float uo=wsb[bUSG+n];
      float wwp=ld_agt(wsb+bWW+n);
      float un=(uo+wwp-uo*wwp)*psi;
      uu[n]=un; wsb[bUSG+n]=un;
      __syncthreads();
      int rk=0;
      #pragma unroll 8
      for (int j=0;j<256;++j){
        float uj=uu[j];
        rk += (uj<un)||(uj==un && j<n);
      }
      sa[rk]=un;
      __syncthreads();
      float* cur=sa; float* nxt=sb;
      for (int off=1;off<256;off<<=1){
        float v=cur[n]; if (n>=off) v*=cur[n-off];
        nxt[n]=v;
        __syncthreads();
        float* tmp=cur; cur=nxt; nxt=tmp;
      }
      float pe = rk ? cur[rk-1] : 1.f;
      float al = (1.f-un)*pe;
      st_agt(wsb+bALC+n, al);
      float sumA = bredsum(al, red);
      if (tid==0){
        st_agt(wsb+bSCL+0, sigm(xv[457]));
        st_agt(wsb+bSCL+1, sigm(xv[458]));
        st_agt(wsb+bSCL+2, sumA);
      }
      {
        int r=tid>>6, m=tid&63;
        float kv=xv[(r<<6)+m];
        float s2=wredsum(kv*kv);
        float br=oneplus_(xv[256+r]);
        st_agt(wsb+bKNR+tid, kv*br/(sqrtf(s2)+1e-6f));
      }
      if (tid<4){
        float p0=xv[459+tid*3], p1=xv[460+tid*3], p2=xv[461+tid*3];
        float mx=fmaxf(p0,fmaxf(p1,p2));
        float e0=expf(p0-mx), e1=expf(p1-mx), e2=expf(p2-mx);
        float sm=e0+e1+e2;
        st_agt(wsb+bPI+tid*3+0, e0/sm);
        st_agt(wsb+bPI+tid*3+1, e1/sm);
        st_agt(wsb+bPI+tid*3+2, e2/sm);
      }
      if (tid<64){
        st_agt(wsb+bERS+tid, sigm(xv[325+tid]));
        st_agt(wsb+bWVC+tid, xv[389+tid]);
      }
    } else if (ci == 1){
      float* knw=smem; float* sims=smem+64; float* red=smem+320;
      const int half = lane>>5, l32 = lane&31;
      if (wv==0){
        float kv=ld_agt(wsb+bXI+260+lane);
        float s2=wredsum(kv*kv);
        float bw_=oneplus_(ld_agt(wsb+bXI+324));
        knw[lane]=kv*bw_/(sqrtf(s2)+1e-6f);
      }
      __syncthreads();
      const float* memb=wsb+bMEM;
      for (int i2=0;i2<32;++i2){
        int n=(wv<<6)+(i2<<1)+half;
        float2 v=ld2_agt(memb+(n<<6)+(l32<<1));
        float d=hredsum32(v.x*knw[l32<<1]+v.y*knw[(l32<<1)+1]);
        if (l32==0) sims[n]=d/(sqrtf(ld_agt(wsb+bNRM+n))+1e-6f);
      }
      __syncthreads();
      float sv=sims[tid];
      float mx=bredmax(sv,red); float e=expf(sv-mx); float sm=bredsum(e,red);
      st_agt(wsb+bCW+tid, e/sm);
    } else if (ci == 2){
      for (int e=tid;e<4096;e+=NT) st_agt(wsb+bBWDP+e, 0.f);
    }
    ep++; cbar(wsb, ep, ci);

    // ================= D: link rows 16ci.. + fwd/bwd partials + mem/nrm/prec =================
    {
      float* wwl   = smem;         // 256
      float* wrl   = smem + 256;   // 4x16
      float* fpart = smem + 320;   // 4wv x 4r x 16
      float* sscl  = smem + 576;   // 4
      const int ri = ci<<4;
      if (tid < 3) sscl[tid] = ld_agt(wsb+bSCL+tid);
      __syncthreads();
      float ga = sscl[0], gw = sscl[1], sA = sscl[2];
      float sww = gw*(ga*sA + (1.f-ga));
      int j = tid;
      float wj = gw*(ga*ld_agt(wsb+bALC+j) + (1.f-ga)*ld_agt(wsb+bCW+j));
      wwl[j] = wj;
      if (ci == 1) st_agt(wsb+bWW+j, wj);
      float pj = ld_agt(wsb+bPRC + (size_t)(t&1)*256 + j);
      if (ci == 0) st_agt(wsb+bPRC + (size_t)((t+1)&1)*256 + j, (1.f-sww)*pj + wj);
      const float* wrb = wsb + bWR;
      float wr0=ld_agt(wrb+j), wr1=ld_agt(wrb+256+j),
            wr2=ld_agt(wrb+512+j), wr3=ld_agt(wrb+768+j);
      if (tid < 64) wrl[(tid>>4)*16 + (tid&15)] = ld_agt(wrb + ((size_t)(tid>>4)<<8) + ri + (tid&15));
      __syncthreads();
      float b0=0.f,b1=0.f,b2=0.f,b3=0.f;
      float* lrow = wsb + bLNK + (size_t)ri*256;   // private, L1/L2-resident
      for (int il=0; il<16; ++il){
        int irow = ri + il;
        float Lo = lrow[il*256 + j];
        float wi = wwl[irow];
        float Ln = (1.f - wi - wj)*Lo + wi*pj;
        if (irow == j) Ln = 0.f;
        lrow[il*256 + j] = Ln;
        float s0=wredsum(Ln*wr0), s1=wredsum(Ln*wr1), s2=wredsum(Ln*wr2), s3=wredsum(Ln*wr3);
        if (lane==0){
          fpart[wv*64 + il]      = s0;
          fpart[wv*64 + 16 + il] = s1;
          fpart[wv*64 + 32 + il] = s2;
          fpart[wv*64 + 48 + il] = s3;
        }
        b0=fmaf(Ln, wrl[il],    b0);
        b1=fmaf(Ln, wrl[16+il], b1);
        b2=fmaf(Ln, wrl[32+il], b2);
        b3=fmaf(Ln, wrl[48+il], b3);
      }
      __syncthreads();
      if (tid < 64){
        int r = tid>>4, il = tid&15;
        float sm = fpart[r*16+il] + fpart[64+r*16+il] + fpart[128+r*16+il] + fpart[192+r*16+il];
        st_agt(wsb+bFWD + ((size_t)r<<8) + ri + il, sm);
      }
      float* slot = wsb + bBWDP + (size_t)(ci&3)*1024;   // 4-way contention only
      atomicAdd(&slot[j], b0);      atomicAdd(&slot[256+j], b1);
      atomicAdd(&slot[512+j], b2);  atomicAdd(&slot[768+j], b3);
      // mem update rows ri..ri+15
      {
        int row2 = tid>>5, c2 = tid&31;
        float2 er  = ld2_agt(wsb+bERS + (c2<<1));
        float2 wv2 = ld2_agt(wsb+bWVC + (c2<<1));
        #pragma unroll
        for (int it=0; it<2; ++it){
          int row = ri + row2 + it*8;
          float wwn = wwl[row];
          float2 v = ld2_agt(wsb+bMEM + ((size_t)row<<6) + (c2<<1));
          v.x = v.x*(1.f - wwn*er.x) + wwn*wv2.x;
          v.y = v.y*(1.f - wwn*er.y) + wwn*wv2.y;
          st2_agt(wsb+bMEM + ((size_t)row<<6) + (c2<<1), v);
          float s2 = hredsum32(v.x*v.x + v.y*v.y);
          if (c2==0) st_agt(wsb+bNRM+row, s2);
        }
      }
    }
    ep++; cbar(wsb, ep, ci);

    // ================= E: read heads (ci<4: head r=ci) =================
    if (ci < 4){
      int r = ci;
      float* knl=smem; float* sims=smem+64; float* wrs=smem+320;
      float* part=smem+576; float* red=smem+832;
      if (wv==0) knl[lane]=ld_agt(wsb+bKNR+(r<<6)+lane);
      __syncthreads();
      const float* memb = wsb + bMEM;
      {
        int row2 = tid>>5, c2 = tid&31;
        for (int it=0; it<32; ++it){
          int n = row2 + it*8;
          float2 v = ld2_agt(memb + ((size_t)n<<6) + (c2<<1));
          float d = hredsum32(v.x*knl[c2<<1] + v.y*knl[(c2<<1)+1]);
          if (c2==0) sims[n] = d/(sqrtf(ld_agt(wsb+bNRM+n))+1e-6f);
        }
      }
      __syncthreads();
      float sv=sims[tid];
      float mx=bredmax(sv,red); float e=expf(sv-mx); float sm=bredsum(e,red);
      float cr=e/sm;
      float p0=ld_agt(wsb+bPI+r*3), p1=ld_agt(wsb+bPI+r*3+1), p2=ld_agt(wsb+bPI+r*3+2);
      float bwv = ld_agt(wsb+bBWDP + ((size_t)r<<8) + tid)
                + ld_agt(wsb+bBWDP + 1024 + ((size_t)r<<8) + tid)
                + ld_agt(wsb+bBWDP + 2048 + ((size_t)r<<8) + tid)
                + ld_agt(wsb+bBWDP + 3072 + ((size_t)r<<8) + tid);
      float wr = p0*bwv + p1*cr + p2*ld_agt(wsb+bFWD+((size_t)r<<8)+tid);
      st_agt(wsb+bWR+((size_t)r<<8)+tid, wr);
      wrs[tid]=wr;
      __syncthreads();
      {
        int m = tid&63, ksn = tid>>6;
        float a=0.f;
        #pragma unroll 8
        for (int n0=0;n0<64;++n0){
          int n = (ksn<<6)+n0;
          a = fmaf(wrs[n], ld_agt(memb + ((size_t)n<<6) + m), a);
        }
        part[(ksn<<6)+m]=a;
      }
      __syncthreads();
      if (tid<64)
        st_sys(wsb+bRV+(r<<6)+tid, part[tid]+part[64+tid]+part[128+tid]+part[192+tid]);
    }
    ep++; cbar(wsb, ep, ci);

    // state flag: rv(t) complete and sys-visible (cbar drained stores)
    if (ci==0 && tid==0)
      __hip_atomic_store((unsigned*)(wsb + bSTF), (unsigned)(t+1),
                         __ATOMIC_RELAXED, __HIP_MEMORY_SCOPE_SYSTEM);
  }

  // ---- epilogue: y(255) = YH + rv(255) @ Wr ----
  {
    float* srv  = smem;        // 256
    float* ysum = smem + 256;  // 256
    for (int e=tid;e<256;e+=NT) srv[e]=ld_sys(wsb+bRV+e);
    __syncthreads();
    int ks2 = tid>>4, cc = tid&15;
    int yc = (ci<<4) + cc;
    float a = 0.f;
    const float* wp = Wr + (size_t)(ks2*16)*256 + yc;
    const float* rp = srv + ks2*16;
    #pragma unroll
    for (int k=0;k<16;++k) a = fmaf(rp[k], wp[(size_t)k*256], a);
    ysum[ks2*16 + cc] = a;
    __syncthreads();
    if (tid < 16){
      float sm = 0.f;
      #pragma unroll
      for (int p=0;p<16;++p) sm += ysum[p*16 + tid];
      int yc2 = (ci<<4) + tid;
      out[((size_t)(b*256 + 255))*256 + yc2] = ld_agt(wsb+bYH+yc2) + sm;
    }
  }
}

extern "C" void kernel_launch(void* const* d_in, const int* in_sizes, int n_in,
                              void* d_out, int out_size, void* d_ws, size_t ws_size,
                              hipStream_t stream) {
  (void)in_sizes; (void)out_size;
  if (n_in < 9) return;
  const float* xin = (const float*)d_in[0];
  const float* Wx  = (const float*)d_in[1];
  const float* Wh  = (const float*)d_in[2];
  const float* bl  = (const float*)d_in[3];
  const float* Wxi = (const float*)d_in[4];
  const float* bxi = (const float*)d_in[5];
  const float* Wy  = (const float*)d_in[6];
  const float* Wr  = (const float*)d_in[7];
  const float* by  = (const float*)d_in[8];
  float* out = (float*)d_out;
  float* ws  = (float*)d_ws;
  if (ws_size < WS_TOTAL*sizeof(float)) return;

  hipLaunchKernelGGL(k_zero, dim3(512), dim3(256), 0, stream, ws);
  hipLaunchKernelGGL(k_dnc, dim3(NB), dim3(NT), 0, stream,
                     xin, Wx, Wh, bl, Wxi, bxi, Wy, Wr, by, out, ws);
}

// Round 14
// 22992.767 us; speedup vs baseline: 1.1087x; 1.1087x over previous
//
#include <hip/hip_runtime.h>
#include <cstddef>

#define DEV __device__ __forceinline__

// ---- dims: B=16 S=256 IN_DIM=264 H=512 4H=2048 XI=471 N=256 M=64 R=4 OUT=256
constexpr int S_ = 256;
constexpr int NB = 256;
constexpr int NT = 256;

// R13 post-mortem: per-step time ~90-110us is invariant to bytes (FETCH 27x),
// hop count, and sync protocol -> suspect global SCLK clamp: ~250 blocks
// s_sleep-polling >90% of the time makes the chip look idle; DVFS drops
// clocks ~4x (identical dispatches vary 25.5<->56.9us = clock-state swing).
// R14 = R10 (best, 23.3ms) with ONE change: cbar backoff s_sleep removed ->
// pure busy spin to hold SCLK up. Single-variable A/B.

// per-batch region offsets (floats), stride PB, base ws + b*PB
constexpr size_t bH    = 0;       // 2x512 h ping-pong [agent]
constexpr size_t bC    = 1024;    // 512 LSTM c [private: block ci=j/32]
constexpr size_t bXI   = 1536;    // 512 (471 used) [agent]
constexpr size_t bKNR  = 2048;    // 256 [agent]
constexpr size_t bALC  = 2304;    // 256 [agent]
constexpr size_t bCW   = 2560;    // 256 [agent]
constexpr size_t bWW   = 2816;    // 256 [agent]
constexpr size_t bNRM  = 3072;    // 256 [agent]
constexpr size_t bUSG  = 3328;    // 256 [private: ctrl block]
constexpr size_t bRV   = 3584;    // 256 [agent]
constexpr size_t bYH   = 3840;    // 256 [agent]
constexpr size_t bSCL  = 4096;    // 32  [agent]
constexpr size_t bPI   = 4128;    // 32  [agent]
constexpr size_t bERS  = 4160;    // 64  [agent]
constexpr size_t bWVC  = 4224;    // 64  [agent]
constexpr size_t bPRC  = 4288;    // 2x256 [agent]
constexpr size_t bWR   = 4800;    // 4x256 [agent]
constexpr size_t bFWD  = 5824;    // 4x256 [agent]
constexpr size_t bBWDP = 6848;    // 4 slots x 4 heads x 256 [agent zero + dev atomicAdd]
constexpr size_t bFLG  = 10944;   // 16 crew flags x 32 (1/128B line)
constexpr size_t bMEM  = 11456;   // 256x64 [agent]
constexpr size_t bLNK  = 27840;   // 256x256 [private: block ci owns rows 16ci..]
constexpr size_t PB    = 93376;
constexpr size_t WS_TOTAL = PB*16;   // ~5.98 MB

typedef unsigned long long u64_;
union F2U { u64_ u; float2 f; };
DEV float2 ld2_agt(const float* p){ F2U c; c.u=__hip_atomic_load((const u64_*)p,__ATOMIC_RELAXED,__HIP_MEMORY_SCOPE_AGENT); return c.f; }
DEV void   st2_agt(float* p, float2 v){ F2U c; c.f=v; __hip_atomic_store((u64_*)p,c.u,__ATOMIC_RELAXED,__HIP_MEMORY_SCOPE_AGENT); }
DEV float  ld_agt(const float* p){ return __hip_atomic_load((float*)p,__ATOMIC_RELAXED,__HIP_MEMORY_SCOPE_AGENT); }
DEV void   st_agt(float* p,float v){ __hip_atomic_store(p,v,__ATOMIC_RELAXED,__HIP_MEMORY_SCOPE_AGENT); }
DEV float  ld_sys(const float* p){ return __hip_atomic_load((float*)p,__ATOMIC_RELAXED,__HIP_MEMORY_SCOPE_SYSTEM); }
DEV void   st_sys(float* p,float v){ __hip_atomic_store(p,v,__ATOMIC_RELAXED,__HIP_MEMORY_SCOPE_SYSTEM); }

DEV float sigm(float x){ return 1.0f/(1.0f+expf(-x)); }
DEV float oneplus_(float x){ float sp = (x>20.0f)? x : log1pf(expf(x)); return 1.0f+sp; }

DEV float wredsum(float v){
  #pragma unroll
  for (int o=32;o>0;o>>=1) v += __shfl_xor(v,o);
  return v;
}
DEV float hredsum32(float v){
  #pragma unroll
  for (int o=16;o>0;o>>=1) v += __shfl_xor(v,o);
  return v;
}
DEV float wredmax(float v){
  #pragma unroll
  for (int o=32;o>0;o>>=1) v = fmaxf(v,__shfl_xor(v,o));
  return v;
}
DEV float bredsum(float v, float* red){
  v = wredsum(v);
  if ((threadIdx.x&63)==0) red[threadIdx.x>>6]=v;
  __syncthreads();
  float r = red[0]+red[1]+red[2]+red[3];
  __syncthreads();
  return r;
}
DEV float bredmax(float v, float* red){
  v = wredmax(v);
  if ((threadIdx.x&63)==0) red[threadIdx.x>>6]=v;
  __syncthreads();
  float r = fmaxf(fmaxf(red[0],red[1]),fmaxf(red[2],red[3]));
  __syncthreads();
  return r;
}

// crew barrier, single-round: post own flag, all poll all 16.
// R14: PURE BUSY SPIN (no s_sleep) — keep the SQ issuing so DVFS holds SCLK.
DEV void cbar(float* wsb, unsigned ep, int ci){
  unsigned* flg = (unsigned*)(wsb + bFLG);
  __syncthreads();
  if (threadIdx.x < 64){
    if (threadIdx.x == 0)
      __hip_atomic_store(flg + (size_t)ci*32, ep, __ATOMIC_RELAXED, __HIP_MEMORY_SCOPE_AGENT);
    const int l = threadIdx.x;
    bool ok;
    do {
      unsigned v = (l<16) ? __hip_atomic_load(flg + (size_t)l*32,
                      __ATOMIC_RELAXED, __HIP_MEMORY_SCOPE_AGENT) : ep;
      ok = __all(v >= ep);
    } while (!ok);
  }
  __syncthreads();
}

__global__ void k_zero(float* __restrict__ ws){
  size_t i = (size_t)blockIdx.x*blockDim.x + threadIdx.x;
  size_t st = (size_t)gridDim.x*blockDim.x;
  for (; i<WS_TOTAL; i+=st) ws[i]=0.0f;
}

__global__ __launch_bounds__(NT, 2) void k_dnc(
    const float* __restrict__ xin, const float* __restrict__ Wx,
    const float* __restrict__ Wh,  const float* __restrict__ bl,
    const float* __restrict__ Wxi, const float* __restrict__ bxi,
    const float* __restrict__ Wy,  const float* __restrict__ Wr,
    const float* __restrict__ by,  float* __restrict__ out,
    float* __restrict__ ws)
{
  __shared__ float smem[14336];   // 57 KB
  const int tid  = threadIdx.x;
  const int bid  = blockIdx.x;
  const int lane = tid & 63, wv = tid >> 6;
  // crew mapping: XCD x = bid%8; q = bid/8; s = q&1; ci = q>>1; batch = x+8s
  const int x  = bid & 7;
  const int q  = bid >> 3;
  const int s  = q & 1;
  const int ci = q >> 1;
  const int b  = x + (s<<3);
  float* wsb = ws + (size_t)b*PB;
  unsigned ep = 0;

  for (int t=0; t<S_; ++t){
    // ================= A: gates GEMM (pipelined) + LSTM + y(t-1) =================
    {
      float* sact = smem;          // 1032 (pad 1040)
      float* sred = smem + 1040;   // 8x128
      float* gall = smem + 2064;   // 128
      float* ysum = smem + 2192;   // 256
      const float* hrd = wsb + bH + (size_t)(t&1)*512;
      float* hwr = wsb + bH + (size_t)((t+1)&1)*512;
      for (int e=tid; e<1032; e+=NT){
        float v;
        if (e < 264)      v = xin[((size_t)(b*256+t))*264 + e];
        else if (e < 520) v = ld_agt(wsb + bRV + (e-264));
        else              v = ld_agt(hrd + (e-520));
        sact[e] = v;
      }
      __syncthreads();
      if (t > 0){  // y(t-1) = YH + rv(t-1)@Wr ; rv staged in sact[264..519]
        int ks2 = tid>>4, cc = tid&15;
        int yc = (ci<<4) + cc;
        float a = 0.f;
        const float* wp = Wr + (size_t)(ks2*16)*256 + yc;
        const float* rp = sact + 264 + ks2*16;
        #pragma unroll
        for (int k=0;k<16;++k) a = fmaf(rp[k], wp[(size_t)k*256], a);
        ysum[ks2*16 + cc] = a;
        __syncthreads();
        if (tid < 16){
          float sm = 0.f;
          #pragma unroll
          for (int p=0;p<16;++p) sm += ysum[p*16 + tid];
          int yc2 = (ci<<4) + tid;
          out[((size_t)(b*256 + (t-1)))*256 + yc2] = ld_agt(wsb+bYH+yc2) + sm;
        }
        __syncthreads();
      }
      // gates GEMM: 128 cols, k=1032, 8-way ksplit, SW-pipelined prefetch
      {
        const int colq = tid & 31;
        const int ksA  = tid >> 5;
        const int g    = colq >> 3;
        const int col  = (g<<9) + (ci<<5) + ((colq&7)<<2);
        float4 acc; acc.x=0.f; acc.y=0.f; acc.z=0.f; acc.w=0.f;
        const float4* wp; const float* xp; int kn;
        if (ksA < 4){
          int k0 = ksA*130; kn = 130;
          wp = (const float4*)(Wx + (size_t)k0*2048 + col);
          xp = sact + k0;
        } else {
          int k0 = (ksA-4)*128; kn = 128;
          wp = (const float4*)(Wh + (size_t)k0*2048 + col);
          xp = sact + 520 + k0;
        }
        const int nch = (kn+7)>>3;
        float4 buf[8];
        #pragma unroll
        for (int i=0;i<8;++i){
          int kk = (i<kn)? i : kn-1;
          buf[i] = wp[(size_t)kk*512];
        }
        for (int c=0; c<nch; ++c){
          float4 nbuf[8];
          int nb0 = (c+1)<<3;
          #pragma unroll
          for (int i=0;i<8;++i){
            int kk = nb0+i; kk = (kk<kn)? kk : kn-1;
            nbuf[i] = wp[(size_t)kk*512];
          }
          int kb = c<<3;
          #pragma unroll
          for (int i=0;i<8;++i){
            float xv = (kb+i<kn)? xp[kb+i] : 0.f;
            acc.x=fmaf(buf[i].x,xv,acc.x); acc.y=fmaf(buf[i].y,xv,acc.y);
            acc.z=fmaf(buf[i].z,xv,acc.z); acc.w=fmaf(buf[i].w,xv,acc.w);
          }
          #pragma unroll
          for (int i=0;i<8;++i) buf[i]=nbuf[i];
        }
        *(float4*)(sred + ksA*128 + (colq<<2)) = acc;
      }
      __syncthreads();
      if (tid < 128){
        int gg = tid>>5, cc = (ci<<5) + (tid&31);
        float sm = bl[(gg<<9)+cc];
        #pragma unroll
        for (int p=0;p<8;++p) sm += sred[(p<<7) + tid];
        gall[tid] = sm;
      }
      __syncthreads();
      if (tid < 32){
        int j = (ci<<5) + tid;
        float gi=gall[tid], gf=gall[32+tid], gg2=gall[64+tid], go=gall[96+tid];
        float co = wsb[bC + j];          // private (same CU every step)
        float cn = sigm(gf)*co + sigm(gi)*tanhf(gg2);
        float hn = sigm(go)*tanhf(cn);
        wsb[bC + j] = cn;
        st_agt(hwr + j, hn);
      }
    }
    ep++; cbar(wsb, ep, ci);

    // ================= B: xi = h@Wxi + bxi ; YH = h@Wy + by =================
    {
      float* shh = smem;         // 512
      float* sp  = smem + 512;   // 8x30
      float* syh = smem + 768;   // 16x16
      const float* hcur = wsb + bH + (size_t)((t+1)&1)*512;
      for (int e=tid; e<512; e+=NT) shh[e] = ld_agt(hcur + e);
      __syncthreads();
      const int nc = (ci<15) ? 30 : 21;
      if (tid < 240){
        int ks = tid/30, cc = tid%30;
        if (cc < nc){
          int col = ci*30 + cc;
          float a = 0.f;
          const float* wp = Wxi + (size_t)(ks*64)*471 + col;
          const float* hp = shh + ks*64;
          #pragma unroll 8
          for (int k=0;k<64;++k) a = fmaf(hp[k], wp[(size_t)k*471], a);
          sp[ks*30 + cc] = a;
        }
      }
      {
        int ks = tid>>4, cc = tid&15;
        int col = (ci<<4) + cc;
        float a = 0.f;
        const float* wp = Wy + (size_t)(ks*32)*256 + col;
        const float* hp = shh + ks*32;
        #pragma unroll 8
        for (int k=0;k<32;++k) a = fmaf(hp[k], wp[(size_t)k*256], a);
        syh[ks*16 + cc] = a;
      }
      __syncthreads();
      if (tid < nc){
        float sm = bxi[ci*30 + tid];
        #pragma unroll
        for (int p=0;p<8;++p) sm += sp[p*30 + tid];
        st_agt(wsb + bXI + ci*30 + tid, sm);
      }
      if (tid < 16){
        float sm = by[(ci<<4) + tid];
        #pragma unroll
        for (int p=0;p<16;++p) sm += syh[p*16 + tid];
        st_agt(wsb + bYH + (ci<<4) + tid, sm);
      }
    }
    ep++; cbar(wsb, ep, ci);

    // ================= C: ctrl(ci0) | content(ci1) | zero BWDP(ci2) =================
    if (ci == 0){
      float* xv = smem; float* uu = smem+512; float* sa = smem+768;
      float* sb = smem+1024; float* red = smem+1280;
      if (tid < 240){
        float2 v = ld2_agt(wsb + bXI + (tid<<1));
        xv[tid<<1]=v.x; xv[(tid<<1)+1]=v.y;
      }
      __syncthreads();
      int n = tid;
      float f0=sigm(xv[453]), f1=sigm(xv[454]), f2v=sigm(xv[455]), f3=sigm(xv[456]);
      const float* wrb = wsb + bWR;
      float psi=(1.f-f0*ld_agt(wrb+n))*(1.f-f1*ld_agt(wrb+256+n))
               *(1.f-f2v*ld_agt(wrb+512+n))*(1.f-f3*ld_agt(wrb+768+n));
      float uo=wsb[bUSG+n];
      float wwp=ld_agt(wsb+bWW+n);
      float un=(uo+wwp-uo*wwp)*psi;
      uu[n]=un; wsb[bUSG+n]=un;
      __syncthreads();
      int rk=0;
      #pragma unroll 8
      for (int j=0;j<256;++j){
        float uj=uu[j];
        rk += (uj<un)||(uj==un && j<n);
      }
      sa[rk]=un;
      __syncthreads();
      float* cur=sa; float* nxt=sb;
      for (int off=1;off<256;off<<=1){
        float v=cur[n]; if (n>=off) v*=cur[n-off];
        nxt[n]=v;
        __syncthreads();
        float* tmp=cur; cur=nxt; nxt=tmp;
      }
      float pe = rk ? cur[rk-1] : 1.f;
      float al = (1.f-un)*pe;
      st_agt(wsb+bALC+n, al);
      float sumA = bredsum(al, red);
      if (tid==0){
        st_agt(wsb+bSCL+0, sigm(xv[457]));
        st_agt(wsb+bSCL+1, sigm(xv[458]));
        st_agt(wsb+bSCL+2, sumA);
      }
      {
        int r=tid>>6, m=tid&63;
        float kv=xv[(r<<6)+m];
        float s2=wredsum(kv*kv);
        float br=oneplus_(xv[256+r]);
        st_agt(wsb+bKNR+tid, kv*br/(sqrtf(s2)+1e-6f));
      }
      if (tid<4){
        float p0=xv[459+tid*3], p1=xv[460+tid*3], p2=xv[461+tid*3];
        float mx=fmaxf(p0,fmaxf(p1,p2));
        float e0=expf(p0-mx), e1=expf(p1-mx), e2=expf(p2-mx);
        float sm=e0+e1+e2;
        st_agt(wsb+bPI+tid*3+0, e0/sm);
        st_agt(wsb+bPI+tid*3+1, e1/sm);
        st_agt(wsb+bPI+tid*3+2, e2/sm);
      }
      if (tid<64){
        st_agt(wsb+bERS+tid, sigm(xv[325+tid]));
        st_agt(wsb+bWVC+tid, xv[389+tid]);
      }
    } else if (ci == 1){
      float* knw=smem; float* sims=smem+64; float* red=smem+320;
      const int half = lane>>5, l32 = lane&31;
      if (wv==0){
        float kv=ld_agt(wsb+bXI+260+lane);
        float s2=wredsum(kv*kv);
        float bw_=oneplus_(ld_agt(wsb+bXI+324));
        knw[lane]=kv*bw_/(sqrtf(s2)+1e-6f);
      }
      __syncthreads();
      const float* memb=wsb+bMEM;
      for (int i2=0;i2<32;++i2){
        int n=(wv<<6)+(i2<<1)+half;
        float2 v=ld2_agt(memb+(n<<6)+(l32<<1));
        float d=hredsum32(v.x*knw[l32<<1]+v.y*knw[(l32<<1)+1]);
        if (l32==0) sims[n]=d/(sqrtf(ld_agt(wsb+bNRM+n))+1e-6f);
      }
      __syncthreads();
      float sv=sims[tid];
      float mx=bredmax(sv,red); float e=expf(sv-mx); float sm=bredsum(e,red);
      st_agt(wsb+bCW+tid, e/sm);
    } else if (ci == 2){
      for (int e=tid;e<4096;e+=NT) st_agt(wsb+bBWDP+e, 0.f);
    }
    ep++; cbar(wsb, ep, ci);

    // ================= D: link rows 16ci.. + fwd/bwd partials + mem/nrm/prec =================
    {
      float* wwl   = smem;         // 256
      float* wrl   = smem + 256;   // 4x16
      float* fpart = smem + 320;   // 4wv x 4r x 16
      float* sscl  = smem + 576;   // 4
      const int ri = ci<<4;
      if (tid < 3) sscl[tid] = ld_agt(wsb+bSCL+tid);
      __syncthreads();
      float ga = sscl[0], gw = sscl[1], sA = sscl[2];
      float sww = gw*(ga*sA + (1.f-ga));
      int j = tid;
      float wj = gw*(ga*ld_agt(wsb+bALC+j) + (1.f-ga)*ld_agt(wsb+bCW+j));
      wwl[j] = wj;
      if (ci == 1) st_agt(wsb+bWW+j, wj);
      float pj = ld_agt(wsb+bPRC + (size_t)(t&1)*256 + j);
      if (ci == 0) st_agt(wsb+bPRC + (size_t)((t+1)&1)*256 + j, (1.f-sww)*pj + wj);
      const float* wrb = wsb + bWR;
      float wr0=ld_agt(wrb+j), wr1=ld_agt(wrb+256+j),
            wr2=ld_agt(wrb+512+j), wr3=ld_agt(wrb+768+j);
      if (tid < 64) wrl[(tid>>4)*16 + (tid&15)] = ld_agt(wrb + ((size_t)(tid>>4)<<8) + ri + (tid&15));
      __syncthreads();
      float b0=0.f,b1=0.f,b2=0.f,b3=0.f;
      float* lrow = wsb + bLNK + (size_t)ri*256;   // private, L1/L2-resident
      for (int il=0; il<16; ++il){
        int irow = ri + il;
        float Lo = lrow[il*256 + j];
        float wi = wwl[irow];
        float Ln = (1.f - wi - wj)*Lo + wi*pj;
        if (irow == j) Ln = 0.f;
        lrow[il*256 + j] = Ln;
        float s0=wredsum(Ln*wr0), s1=wredsum(Ln*wr1), s2=wredsum(Ln*wr2), s3=wredsum(Ln*wr3);
        if (lane==0){
          fpart[wv*64 + il]      = s0;
          fpart[wv*64 + 16 + il] = s1;
          fpart[wv*64 + 32 + il] = s2;
          fpart[wv*64 + 48 + il] = s3;
        }
        b0=fmaf(Ln, wrl[il],    b0);
        b1=fmaf(Ln, wrl[16+il], b1);
        b2=fmaf(Ln, wrl[32+il], b2);
        b3=fmaf(Ln, wrl[48+il], b3);
      }
      __syncthreads();
      if (tid < 64){
        int r = tid>>4, il = tid&15;
        float sm = fpart[r*16+il] + fpart[64+r*16+il] + fpart[128+r*16+il] + fpart[192+r*16+il];
        st_agt(wsb+bFWD + ((size_t)r<<8) + ri + il, sm);
      }
      float* slot = wsb + bBWDP + (size_t)(ci&3)*1024;   // 4-way contention only
      atomicAdd(&slot[j], b0);      atomicAdd(&slot[256+j], b1);
      atomicAdd(&slot[512+j], b2);  atomicAdd(&slot[768+j], b3);
      // mem update rows ri..ri+15
      {
        int row2 = tid>>5, c2 = tid&31;
        float2 er  = ld2_agt(wsb+bERS + (c2<<1));
        float2 wv2 = ld2_agt(wsb+bWVC + (c2<<1));
        #pragma unroll
        for (int it=0; it<2; ++it){
          int row = ri + row2 + it*8;
          float wwn = wwl[row];
          float2 v = ld2_agt(wsb+bMEM + ((size_t)row<<6) + (c2<<1));
          v.x = v.x*(1.f - wwn*er.x) + wwn*wv2.x;
          v.y = v.y*(1.f - wwn*er.y) + wwn*wv2.y;
          st2_agt(wsb+bMEM + ((size_t)row<<6) + (c2<<1), v);
          float s2 = hredsum32(v.x*v.x + v.y*v.y);
          if (c2==0) st_agt(wsb+bNRM+row, s2);
        }
      }
    }
    ep++; cbar(wsb, ep, ci);

    // ================= E: read heads (ci<4: head r=ci) =================
    if (ci < 4){
      int r = ci;
      float* knl=smem; float* sims=smem+64; float* wrs=smem+320;
      float* part=smem+576; float* red=smem+832;
      if (wv==0) knl[lane]=ld_agt(wsb+bKNR+(r<<6)+lane);
      __syncthreads();
      const float* memb = wsb + bMEM;
      {
        int row2 = tid>>5, c2 = tid&31;
        for (int it=0; it<32; ++it){
          int n = row2 + it*8;
          float2 v = ld2_agt(memb + ((size_t)n<<6) + (c2<<1));
          float d = hredsum32(v.x*knl[c2<<1] + v.y*knl[(c2<<1)+1]);
          if (c2==0) sims[n] = d/(sqrtf(ld_agt(wsb+bNRM+n))+1e-6f);
        }
      }
      __syncthreads();
      float sv=sims[tid];
      float mx=bredmax(sv,red); float e=expf(sv-mx); float sm=bredsum(e,red);
      float cr=e/sm;
      float p0=ld_agt(wsb+bPI+r*3), p1=ld_agt(wsb+bPI+r*3+1), p2=ld_agt(wsb+bPI+r*3+2);
      float bwv = ld_agt(wsb+bBWDP + ((size_t)r<<8) + tid)
                + ld_agt(wsb+bBWDP + 1024 + ((size_t)r<<8) + tid)
                + ld_agt(wsb+bBWDP + 2048 + ((size_t)r<<8) + tid)
                + ld_agt(wsb+bBWDP + 3072 + ((size_t)r<<8) + tid);
      float wr = p0*bwv + p1*cr + p2*ld_agt(wsb+bFWD+((size_t)r<<8)+tid);
      st_agt(wsb+bWR+((size_t)r<<8)+tid, wr);
      wrs[tid]=wr;
      __syncthreads();
      {
        int m = tid&63, ksn = tid>>6;
        float a=0.f;
        #pragma unroll 8
        for (int n0=0;n0<64;++n0){
          int n = (ksn<<6)+n0;
          a = fmaf(wrs[n], ld_agt(memb + ((size_t)n<<6) + m), a);
        }
        part[(ksn<<6)+m]=a;
      }
      __syncthreads();
      if (tid<64)
        st_agt(wsb+bRV+(r<<6)+tid, part[tid]+part[64+tid]+part[128+tid]+part[192+tid]);
    }
    ep++; cbar(wsb, ep, ci);
  }

  // ---- epilogue: y(255) = YH + rv(255) @ Wr ----
  {
    float* srv  = smem;        // 256
    float* ysum = smem + 256;  // 256
    for (int e=tid;e<256;e+=NT) srv[e]=ld_agt(wsb+bRV+e);
    __syncthreads();
    int ks2 = tid>>4, cc = tid&15;
    int yc = (ci<<4) + cc;
    float a = 0.f;
    const float* wp = Wr + (size_t)(ks2*16)*256 + yc;
    const float* rp = srv + ks2*16;
    #pragma unroll
    for (int k=0;k<16;++k) a = fmaf(rp[k], wp[(size_t)k*256], a);
    ysum[ks2*16 + cc] = a;
    __syncthreads();
    if (tid < 16){
      float sm = 0.f;
      #pragma unroll
      for (int p=0;p<16;++p) sm += ysum[p*16 + tid];
      int yc2 = (ci<<4) + tid;
      out[((size_t)(b*256 + 255))*256 + yc2] = ld_agt(wsb+bYH+yc2) + sm;
    }
  }
}

extern "C" void kernel_launch(void* const* d_in, const int* in_sizes, int n_in,
                              void* d_out, int out_size, void* d_ws, size_t ws_size,
                              hipStream_t stream) {
  (void)in_sizes; (void)out_size;
  if (n_in < 9) return;
  const float* xin = (const float*)d_in[0];
  const float* Wx  = (const float*)d_in[1];
  const float* Wh  = (const float*)d_in[2];
  const float* bl  = (const float*)d_in[3];
  const float* Wxi = (const float*)d_in[4];
  const float* bxi = (const float*)d_in[5];
  const float* Wy  = (const float*)d_in[6];
  const float* Wr  = (const float*)d_in[7];
  const float* by  = (const float*)d_in[8];
  float* out = (float*)d_out;
  float* ws  = (float*)d_ws;
  if (ws_size < WS_TOTAL*sizeof(float)) return;

  hipLaunchKernelGGL(k_zero, dim3(512), dim3(256), 0, stream, ws);
  hipLaunchKernelGGL(k_dnc, dim3(NB), dim3(NT), 0, stream,
                     xin, Wx, Wh, bl, Wxi, bxi, Wy, Wr, by, out, ws);
}